// Round 4
// baseline (1802.127 us; speedup 1.0000x reference)
//
#include <hip/hip_runtime.h>

#define HDIM 1024
#define SDIM 4096
#define BDIM 16

// u[h] = sum_k v[k] * W[k*2H + H + h]
// Split-K: block kb covers k in [kb*16, kb*16+16); thread t owns h = t*4..t*4+3.
// 64 blocks x 256 threads; 4 atomicAdds/thread (64 adds per address total).
__global__ __launch_bounds__(256) void compute_u_kernel(
    const float* __restrict__ W, const float* __restrict__ v,
    float* __restrict__ u) {
    int t  = threadIdx.x;      // 0..255 -> h4 = t*4
    int kb = blockIdx.x;       // 0..63
    float ax = 0.f, ay = 0.f, az = 0.f, aw = 0.f;
    #pragma unroll
    for (int i = 0; i < 16; ++i) {
        int k = kb * 16 + i;
        float vk = v[k];  // uniform across threads -> broadcast, cached
        float4 w = *(const float4*)&W[(size_t)k * (2 * HDIM) + HDIM + t * 4];
        ax = fmaf(vk, w.x, ax);
        ay = fmaf(vk, w.y, ay);
        az = fmaf(vk, w.z, az);
        aw = fmaf(vk, w.w, aw);
    }
    atomicAdd(&u[t * 4 + 0], ax);
    atomicAdd(&u[t * 4 + 1], ay);
    atomicAdd(&u[t * 4 + 2], az);
    atomicAdd(&u[t * 4 + 3], aw);
}

// One wave (64 lanes) per row: energy[row] = dot(enc[row, :], u).
// Fused softmax: blocks [1024*b, 1024*(b+1)) produce batch b's 4096 energies;
// the last block to finish (per-batch atomic counter) softmaxes that batch.
__global__ __launch_bounds__(256) void energies_softmax_kernel(
    const float4* __restrict__ enc, const float4* __restrict__ u4,
    float* __restrict__ out, unsigned int* __restrict__ cnt) {
    int wid  = (int)((blockIdx.x * blockDim.x + threadIdx.x) >> 6);
    int lane = threadIdx.x & 63;
    const float4* row = enc + (size_t)wid * (HDIM / 4);
    float acc = 0.f;
    #pragma unroll
    for (int i = 0; i < 4; ++i) {
        float4 e = row[lane + i * 64];
        float4 w = u4[lane + i * 64];
        acc += e.x * w.x + e.y * w.y + e.z * w.z + e.w * w.w;
    }
    #pragma unroll
    for (int off = 32; off > 0; off >>= 1)
        acc += __shfl_down(acc, off, 64);
    if (lane == 0) out[wid] = acc;

    // ---- last-block-done softmax for this batch ----
    int batch = (int)(blockIdx.x >> 10);  // 1024 blocks per batch
    __shared__ unsigned int s_last;
    __threadfence();        // release: make this thread's energy store visible
    __syncthreads();        // all waves' stores+fences complete
    if (threadIdx.x == 0) {
        unsigned int old = atomicAdd(&cnt[batch], 1u);
        s_last = (old == 1023u) ? 1u : 0u;
    }
    __syncthreads();
    if (s_last == 0u) return;

    __threadfence();        // acquire: see all 1024 blocks' energy stores
    float* ob = out + (size_t)batch * SDIM;
    int t = threadIdx.x;
    int wave = t >> 6, lane2 = t & 63;
    __shared__ float red[4];

    float e[16];
    #pragma unroll
    for (int i = 0; i < 16; ++i) e[i] = ob[i * 256 + t];

    float m = e[0];
    #pragma unroll
    for (int i = 1; i < 16; ++i) m = fmaxf(m, e[i]);
    #pragma unroll
    for (int off = 32; off > 0; off >>= 1)
        m = fmaxf(m, __shfl_down(m, off, 64));
    if (lane2 == 0) red[wave] = m;
    __syncthreads();
    m = fmaxf(fmaxf(red[0], red[1]), fmaxf(red[2], red[3]));
    __syncthreads();  // everyone has read red[] for max before reuse

    float x[16], s = 0.f;
    #pragma unroll
    for (int i = 0; i < 16; ++i) { x[i] = __expf(e[i] - m); s += x[i]; }
    #pragma unroll
    for (int off = 32; off > 0; off >>= 1)
        s += __shfl_down(s, off, 64);
    if (lane2 == 0) red[wave] = s;
    __syncthreads();
    float inv = 1.f / (red[0] + red[1] + red[2] + red[3]);

    #pragma unroll
    for (int i = 0; i < 16; ++i) ob[i * 256 + t] = x[i] * inv;
}

extern "C" void kernel_launch(void* const* d_in, const int* in_sizes, int n_in,
                              void* d_out, int out_size, void* d_ws, size_t ws_size,
                              hipStream_t stream) {
    // inputs: 0=hidden (unused: softmax shift-invariance), 1=encoder_outputs,
    //         2=W, 3=b (unused), 4=v
    const float* enc = (const float*)d_in[1];
    const float* W   = (const float*)d_in[2];
    const float* v   = (const float*)d_in[4];
    float* out = (float*)d_out;
    float* u   = (float*)d_ws;                            // 1024 floats = 4 KB
    unsigned int* cnt = (unsigned int*)((char*)d_ws + 4096);  // 16 uints

    // zero u + per-batch counters each call (deterministic, self-contained)
    hipMemsetAsync(d_ws, 0, 8192, stream);

    compute_u_kernel<<<64, 256, 0, stream>>>(W, v, u);

    // 4 waves per 256-thread block, one wave per (b,s) row; softmax fused
    energies_softmax_kernel<<<(BDIM * SDIM) / 4, 256, 0, stream>>>(
        (const float4*)enc, (const float4*)u, out, cnt);
}

// Round 5
// 50.590 us; speedup vs baseline: 35.6220x; 35.6220x over previous
//
#include <hip/hip_runtime.h>

#define HDIM 1024
#define SDIM 4096
#define BDIM 16

// u[h] = sum_k v[k] * W[k*2H + H + h]
// h-split, atomic-free: block b owns h in [16b, 16b+16). Thread t = (kc, hl),
// kc = t>>4 (16 k-chunks of 64), hl = t&15. LDS-reduce over kc, single store.
// No memset needed, no atomics.
__global__ __launch_bounds__(256) void compute_u_kernel(
    const float* __restrict__ W, const float* __restrict__ v,
    float* __restrict__ u) {
    __shared__ float part[16][17];  // [kc][hl], +1 pad
    int t  = threadIdx.x;
    int hl = t & 15;
    int kc = t >> 4;
    int h  = blockIdx.x * 16 + hl;
    float acc = 0.f;
    #pragma unroll 8
    for (int i = 0; i < 64; ++i) {
        int k = kc * 64 + i;
        acc = fmaf(v[k], W[(size_t)k * (2 * HDIM) + HDIM + h], acc);
    }
    part[kc][hl] = acc;
    __syncthreads();
    if (t < 16) {
        float s = 0.f;
        #pragma unroll
        for (int i = 0; i < 16; ++i) s += part[i][t];
        u[blockIdx.x * 16 + t] = s;
    }
}

// One wave (64 lanes) per row: energy[row] = dot(enc[row, :], u)  [R2 body]
__global__ __launch_bounds__(256) void energies_kernel(
    const float4* __restrict__ enc, const float4* __restrict__ u,
    float* __restrict__ out) {
    int wid  = (int)((blockIdx.x * blockDim.x + threadIdx.x) >> 6);
    int lane = threadIdx.x & 63;
    const float4* row = enc + (size_t)wid * (HDIM / 4);
    float acc = 0.f;
    #pragma unroll
    for (int i = 0; i < 4; ++i) {
        float4 e = row[lane + i * 64];
        float4 w = u[lane + i * 64];
        acc += e.x * w.x + e.y * w.y + e.z * w.z + e.w * w.w;
    }
    #pragma unroll
    for (int off = 32; off > 0; off >>= 1)
        acc += __shfl_down(acc, off, 64);
    if (lane == 0) out[wid] = acc;
}

// One block per batch row: in-place softmax over SDIM values.  [R2 body]
__global__ __launch_bounds__(1024) void softmax_kernel(float* __restrict__ out) {
    __shared__ float red[16];
    float* row = out + (size_t)blockIdx.x * SDIM;
    int t = threadIdx.x;
    int wave = t >> 6, lane = t & 63;

    float e0 = row[t];
    float e1 = row[t + 1024];
    float e2 = row[t + 2048];
    float e3 = row[t + 3072];

    // block max
    float m = fmaxf(fmaxf(e0, e1), fmaxf(e2, e3));
    #pragma unroll
    for (int off = 32; off > 0; off >>= 1)
        m = fmaxf(m, __shfl_down(m, off, 64));
    if (lane == 0) red[wave] = m;
    __syncthreads();
    if (t < 16) {
        float mm = red[t];
        #pragma unroll
        for (int off = 8; off > 0; off >>= 1)
            mm = fmaxf(mm, __shfl_down(mm, off, 16));
        if (t == 0) red[0] = mm;
    }
    __syncthreads();
    m = red[0];
    __syncthreads();

    // exp + block sum
    float x0 = __expf(e0 - m);
    float x1 = __expf(e1 - m);
    float x2 = __expf(e2 - m);
    float x3 = __expf(e3 - m);
    float s = x0 + x1 + x2 + x3;
    #pragma unroll
    for (int off = 32; off > 0; off >>= 1)
        s += __shfl_down(s, off, 64);
    if (lane == 0) red[wave] = s;
    __syncthreads();
    if (t < 16) {
        float ss = red[t];
        #pragma unroll
        for (int off = 8; off > 0; off >>= 1)
            ss += __shfl_down(ss, off, 16);
        if (t == 0) red[0] = ss;
    }
    __syncthreads();
    float inv = 1.f / red[0];

    row[t]        = x0 * inv;
    row[t + 1024] = x1 * inv;
    row[t + 2048] = x2 * inv;
    row[t + 3072] = x3 * inv;
}

extern "C" void kernel_launch(void* const* d_in, const int* in_sizes, int n_in,
                              void* d_out, int out_size, void* d_ws, size_t ws_size,
                              hipStream_t stream) {
    // inputs: 0=hidden (unused: softmax shift-invariance), 1=encoder_outputs,
    //         2=W, 3=b (unused), 4=v
    const float* enc = (const float*)d_in[1];
    const float* W   = (const float*)d_in[2];
    const float* v   = (const float*)d_in[4];
    float* out = (float*)d_out;
    float* u   = (float*)d_ws;  // HDIM floats = 4 KB scratch

    compute_u_kernel<<<64, 256, 0, stream>>>(W, v, u);

    // 4 waves per 256-thread block, one wave per (b,s) row
    energies_kernel<<<(BDIM * SDIM) / 4, 256, 0, stream>>>(
        (const float4*)enc, (const float4*)u, out);

    softmax_kernel<<<BDIM, 1024, 0, stream>>>(out);
}